// Round 1
// baseline (40.107 us; speedup 1.0000x reference)
//
#include <hip/hip_runtime.h>

#define SEQL 128
#define DM   512
#define NH   8
#define HD   64

// rp_bucket[i][j] with rel_pos = i - j  =>  n = -rel_pos = j - i
__device__ __forceinline__ int rel_bucket(int i, int j) {
    int n = j - i;
    int ret = 0;
    if (n < 0) { ret = 16; n = -n; }
    if (n < 8) return ret + n;                       // is_small
    float nf = (float)n;                             // n >= 8, so max(n,1)=n
    int vil = 8 + (int)((logf(nf * 0.125f) / logf(16.0f)) * 8.0f);
    vil = vil < 15 ? vil : 15;
    return ret + vil;
}

// h = embed[x] * rsqrt(mean(h^2)+eps) * scale * mask   (one block per row)
__global__ __launch_bounds__(128) void k_embed_rms(
    const int* __restrict__ x, const int* __restrict__ xlen,
    const float* __restrict__ embed, const float* __restrict__ scale,
    float* __restrict__ h) {
    const int r = blockIdx.x;
    const int t = threadIdx.x;          // 0..127, 4 floats each
    const int tok = x[r];
    const float4 e4 = reinterpret_cast<const float4*>(embed + (size_t)tok * DM)[t];
    float ss = e4.x*e4.x + e4.y*e4.y + e4.z*e4.z + e4.w*e4.w;
#pragma unroll
    for (int o = 32; o > 0; o >>= 1) ss += __shfl_down(ss, o);
    __shared__ float part[2];
    if ((t & 63) == 0) part[t >> 6] = ss;
    __syncthreads();
    const float var = (part[0] + part[1]) * (1.0f / DM);
    float inv = rsqrtf(var + 1e-6f);
    if (r >= xlen[0]) inv = 0.0f;       // fold length mask (exact 0)
    const float4 s4 = reinterpret_cast<const float4*>(scale)[t];
    float4 o4;
    o4.x = e4.x * inv * s4.x;
    o4.y = e4.y * inv * s4.y;
    o4.z = e4.z * inv * s4.z;
    o4.w = e4.w * inv * s4.w;
    reinterpret_cast<float4*>(h)[r * (DM / 4) + t] = o4;
}

// C(128x512) = h(128x512) @ W(512x512), written head-split: O[(n>>6)*128+m][n&63]
// grid = (8 n-tiles, 2 m-tiles, 3 weights), 256 thr, 64x64 tile, 4x4/thread
__global__ __launch_bounds__(256) void k_qkv(
    const float* __restrict__ h, const float* __restrict__ qw,
    const float* __restrict__ kw, const float* __restrict__ vw,
    float* __restrict__ q, float* __restrict__ k, float* __restrict__ v) {
    const float* __restrict__ W = (blockIdx.z == 0) ? qw : (blockIdx.z == 1) ? kw : vw;
    float* __restrict__ O       = (blockIdx.z == 0) ? q  : (blockIdx.z == 1) ? k  : v;
    __shared__ float As[32][68];   // [kk][m], stride 68 floats = 272B (16B-aligned rows)
    __shared__ float Ws[32][68];   // [kk][n]
    const int tid = threadIdx.x;
    const int m0 = blockIdx.y * 64;
    const int n0 = blockIdx.x * 64;
    const int tx = tid & 15, ty = tid >> 4;
    float acc[4][4] = {};
    for (int k0 = 0; k0 < DM; k0 += 32) {
#pragma unroll
        for (int i = 0; i < 8; ++i) {               // A tile 64x32
            int e = tid + i * 256;
            As[e & 31][e >> 5] = h[(m0 + (e >> 5)) * DM + k0 + (e & 31)];
        }
#pragma unroll
        for (int i = 0; i < 8; ++i) {               // W tile 32x64 (coalesced)
            int e = tid + i * 256;
            Ws[e >> 6][e & 63] = W[(k0 + (e >> 6)) * DM + n0 + (e & 63)];
        }
        __syncthreads();
#pragma unroll
        for (int kk = 0; kk < 32; ++kk) {
            const float4 av = *reinterpret_cast<const float4*>(&As[kk][ty * 4]);
            const float4 bv = *reinterpret_cast<const float4*>(&Ws[kk][tx * 4]);
            const float a[4] = {av.x, av.y, av.z, av.w};
            const float b[4] = {bv.x, bv.y, bv.z, bv.w};
#pragma unroll
            for (int i = 0; i < 4; ++i)
#pragma unroll
                for (int j = 0; j < 4; ++j) acc[i][j] += a[i] * b[j];
        }
        __syncthreads();
    }
#pragma unroll
    for (int i = 0; i < 4; ++i)
#pragma unroll
        for (int j = 0; j < 4; ++j) {
            const int mm = m0 + ty * 4 + i;
            const int nn = n0 + tx * 4 + j;
            O[((nn >> 6) * SEQL + mm) * HD + (nn & 63)] = acc[i][j];
        }
}

// One wave per (head, query). Also produces rel_bias and attn_weights outputs.
__global__ __launch_bounds__(256) void k_attn(
    const float* __restrict__ q, const float* __restrict__ k,
    const float* __restrict__ v, const int* __restrict__ xlen,
    const float* __restrict__ rbw,
    float* __restrict__ relb, float* __restrict__ aw, float* __restrict__ ao) {
    const int hh = blockIdx.x;
    const int q0 = blockIdx.y * 4;
    __shared__ float Ks[SEQL][HD + 1];   // pad: logits read lane->row, (lane*65+d)%32 = 2-way (free)
    __shared__ float qs[4][HD];
    __shared__ float ps[4][SEQL];
    const int tid = threadIdx.x;
    const float* __restrict__ kb = k + hh * SEQL * HD;
    const float* __restrict__ vb = v + hh * SEQL * HD;
#pragma unroll
    for (int i = 0; i < 32; ++i) {       // stage K head: 8192 floats
        const int e = tid + i * 256;
        Ks[e >> 6][e & 63] = kb[e];
    }
    const int w = tid >> 6, lane = tid & 63;
    const int qi = q0 + w;
    qs[w][lane] = q[(hh * SEQL + qi) * HD + lane];
    __syncthreads();
    const int xl = xlen[0];
    float lg[2];
#pragma unroll
    for (int p = 0; p < 2; ++p) {        // 2 keys per lane
        const int kk = lane + p * 64;
        float acc = 0.0f;
#pragma unroll
        for (int d = 0; d < HD; ++d) acc += qs[w][d] * Ks[kk][d];
        float bias = rbw[hh * 32 + rel_bucket(kk, qi)];
        if (kk >= xl) bias += -1e9f;
        relb[hh * SEQL * SEQL + kk * SEQL + qi] = bias;   // rel_bias output (each elem once)
        acc += bias;
        lg[p] = acc;
        aw[hh * SEQL * SEQL + qi * SEQL + kk] = acc;      // attn_weights output
    }
    // wave softmax over 128 logits (2/lane)
    float mx = fmaxf(lg[0], lg[1]);
#pragma unroll
    for (int o = 32; o > 0; o >>= 1) mx = fmaxf(mx, __shfl_xor(mx, o));
    const float e0 = expf(lg[0] - mx);
    const float e1 = expf(lg[1] - mx);
    float sm = e0 + e1;
#pragma unroll
    for (int o = 32; o > 0; o >>= 1) sm += __shfl_xor(sm, o);
    const float inv = 1.0f / sm;
    ps[w][lane]      = e0 * inv;
    ps[w][lane + 64] = e1 * inv;
    __syncthreads();
    // PV: lane owns output dim d=lane; V read from global (L1-resident, coalesced)
    float acc = 0.0f;
#pragma unroll 8
    for (int kk = 0; kk < SEQL; ++kk) acc += ps[w][kk] * vb[kk * HD + lane];
    ao[(hh * SEQL + qi) * HD + lane] = acc;
}

extern "C" void kernel_launch(void* const* d_in, const int* in_sizes, int n_in,
                              void* d_out, int out_size, void* d_ws, size_t ws_size,
                              hipStream_t stream) {
    const int*   x     = (const int*)d_in[0];
    const int*   xlen  = (const int*)d_in[1];
    const float* embed = (const float*)d_in[2];
    const float* scale = (const float*)d_in[3];
    const float* rbw   = (const float*)d_in[4];
    const float* qw    = (const float*)d_in[5];
    const float* kw    = (const float*)d_in[6];
    const float* vw    = (const float*)d_in[7];

    float* out  = (float*)d_out;
    float* relb = out;                          // (8,128,128)
    float* aw   = out + NH * SEQL * SEQL;       // (8,128,128)
    float* ao   = out + 2 * NH * SEQL * SEQL;   // (8,128,64)

    float* ws = (float*)d_ws;
    float* h  = ws;                    // 128*512
    float* q  = ws + 1 * SEQL * DM;    // (8,128,64) head-split
    float* k  = ws + 2 * SEQL * DM;
    float* v  = ws + 3 * SEQL * DM;

    k_embed_rms<<<SEQL, 128, 0, stream>>>(x, xlen, embed, scale, h);
    k_qkv<<<dim3(8, 2, 3), 256, 0, stream>>>(h, qw, kw, vw, q, k, v);
    k_attn<<<dim3(NH, SEQL / 4), 256, 0, stream>>>(q, k, v, xlen, rbw, relb, aw, ao);
}

// Round 2
// 23.820 us; speedup vs baseline: 1.6838x; 1.6838x over previous
//
#include <hip/hip_runtime.h>

#define SEQL 128
#define DM   512
#define NH   8
#define HD   64

typedef unsigned short ushort_t;
typedef unsigned int   uint_t;
typedef __attribute__((ext_vector_type(8))) __bf16 bf16x8;
typedef __attribute__((ext_vector_type(4))) float  f32x4;

__device__ __forceinline__ ushort_t f2bf(float f) {
    uint_t u = __float_as_uint(f);
    u += 0x7fffu + ((u >> 16) & 1u);       // RNE
    return (ushort_t)(u >> 16);
}

__device__ __forceinline__ void gld_lds16(const void* g, void* l) {
    __builtin_amdgcn_global_load_lds(
        (const __attribute__((address_space(1))) uint_t*)g,
        (__attribute__((address_space(3))) uint_t*)l, 16, 0, 0);
}

// rp_bucket with rel_pos = i - j  =>  n = -rel_pos = j - i
__device__ __forceinline__ int rel_bucket(int i, int j) {
    int n = j - i;
    int ret = 0;
    if (n < 0) { ret = 16; n = -n; }
    if (n < 8) return ret + n;
    float nf = (float)n;
    int vil = 8 + (int)((logf(nf * 0.125f) / logf(16.0f)) * 8.0f);
    vil = vil < 15 ? vil : 15;
    return ret + vil;
}

// blocks 0..127: h row = embed[x]*rsqrt(mean sq)*scale*mask -> bf16
// blocks 128..319: transpose-cast W (3 x 512x512) -> Wt[n][k] bf16
__global__ __launch_bounds__(256) void k_prep(
    const int* __restrict__ x, const int* __restrict__ xlen,
    const float* __restrict__ embed, const float* __restrict__ scale,
    const float* __restrict__ qw, const float* __restrict__ kw,
    const float* __restrict__ vw,
    ushort_t* __restrict__ hbf, ushort_t* __restrict__ wt) {
    const int b = blockIdx.x;
    const int t = threadIdx.x;
    if (b < SEQL) {
        const int tok = x[b];
        const float2 e = reinterpret_cast<const float2*>(embed + (size_t)tok * DM)[t];
        float ss = e.x * e.x + e.y * e.y;
#pragma unroll
        for (int o = 32; o > 0; o >>= 1) ss += __shfl_xor(ss, o);
        __shared__ float part[4];
        if ((t & 63) == 0) part[t >> 6] = ss;
        __syncthreads();
        const float var = (part[0] + part[1] + part[2] + part[3]) * (1.0f / DM);
        float inv = rsqrtf(var + 1e-6f);
        if (b >= xlen[0]) inv = 0.0f;       // length mask (exact zero)
        const float2 s = reinterpret_cast<const float2*>(scale)[t];
        ushort2 u2;
        u2.x = f2bf(e.x * inv * s.x);
        u2.y = f2bf(e.y * inv * s.y);
        reinterpret_cast<ushort2*>(hbf + b * DM)[t] = u2;
    } else {
        const int bw = b - SEQL;                       // 0..191
        const int wi = bw >> 6;                        // weight id
        const int k0 = (bw & 63) * 8;                  // k-slab of 8
        const float* __restrict__ W = (wi == 0) ? qw : (wi == 1) ? kw : vw;
        ushort_t* __restrict__ Wt = wt + (size_t)wi * DM * DM;
#pragma unroll
        for (int rep = 0; rep < 2; ++rep) {
            const int n = t + rep * 256;
            float v[8];
#pragma unroll
            for (int i = 0; i < 8; ++i) v[i] = W[(size_t)(k0 + i) * DM + n]; // coalesced
            ushort_t tmp[8];
#pragma unroll
            for (int i = 0; i < 8; ++i) tmp[i] = f2bf(v[i]);
            *reinterpret_cast<uint4*>(Wt + (size_t)n * DM + k0) =
                *reinterpret_cast<const uint4*>(tmp);
        }
    }
}

// C(128x512) = h @ W  for 3 weights, MFMA bf16, output head-split fp32.
// grid = (8 n-tiles, 2 m-tiles, 3 w), 256 thr = 4 waves (2m x 2n), wave tile 32x32.
// LDS: A[2][64][32] bf16 + B[2][64][32] bf16 (double-buffered, linear, BK=32).
__global__ __launch_bounds__(256) void k_qkv(
    const ushort_t* __restrict__ hbf, const ushort_t* __restrict__ wt,
    float* __restrict__ q, float* __restrict__ k, float* __restrict__ v) {
    __shared__ ushort_t Ash[2][64 * 32];
    __shared__ ushort_t Bsh[2][64 * 32];
    const int t  = threadIdx.x;
    const int n0 = blockIdx.x * 64;
    const int m0 = blockIdx.y * 64;
    const int wi = blockIdx.z;
    const ushort_t* __restrict__ wp = wt + (size_t)wi * DM * DM;
    float* __restrict__ O = (wi == 0) ? q : (wi == 1) ? k : v;

    const int wid = t >> 6, lane = t & 63;
    const int wm = wid >> 1, wn = wid & 1;

    // staging: slot t -> row t>>2, 16B chunk t&3 (linear LDS, matches lane x 16B)
    const int srow = t >> 2, sch = t & 3;
    const ushort_t* asrc = hbf + (size_t)(m0 + srow) * DM + sch * 8;
    const ushort_t* bsrc = wp  + (size_t)(n0 + srow) * DM + sch * 8;
    char* aldst = (char*)Ash + t * 16;
    char* bldst = (char*)Bsh + t * 16;

    // fragment read offsets: A[row = .. + (lane&15)][k = (lane>>4)*8 + i]
    const int arow0 = wm * 32 + (lane & 15);
    const int brow0 = wn * 32 + (lane & 15);
    const int g16   = (lane >> 4) * 16;

    f32x4 acc[2][2] = {};

    gld_lds16(asrc, aldst);
    gld_lds16(bsrc, bldst);
    __syncthreads();

    for (int it = 0; it < 16; ++it) {
        const int cur = it & 1;
        if (it + 1 < 16) {                               // prefetch next K-tile
            gld_lds16(asrc + (it + 1) * 32, aldst + (cur ^ 1) * 4096);
            gld_lds16(bsrc + (it + 1) * 32, bldst + (cur ^ 1) * 4096);
        }
        const char* ab = (const char*)Ash + cur * 4096;
        const char* bb = (const char*)Bsh + cur * 4096;
        bf16x8 a0 = *(const bf16x8*)(ab + (arow0)      * 64 + g16);
        bf16x8 a1 = *(const bf16x8*)(ab + (arow0 + 16) * 64 + g16);
        bf16x8 b0 = *(const bf16x8*)(bb + (brow0)      * 64 + g16);
        bf16x8 b1 = *(const bf16x8*)(bb + (brow0 + 16) * 64 + g16);
        acc[0][0] = __builtin_amdgcn_mfma_f32_16x16x32_bf16(a0, b0, acc[0][0], 0, 0, 0);
        acc[0][1] = __builtin_amdgcn_mfma_f32_16x16x32_bf16(a0, b1, acc[0][1], 0, 0, 0);
        acc[1][0] = __builtin_amdgcn_mfma_f32_16x16x32_bf16(a1, b0, acc[1][0], 0, 0, 0);
        acc[1][1] = __builtin_amdgcn_mfma_f32_16x16x32_bf16(a1, b1, acc[1][1], 0, 0, 0);
        __syncthreads();   // drains prefetch vmcnt + protects cur buffer reuse
    }

    // C/D layout (verified): col = lane&15, row = (lane>>4)*4 + reg
#pragma unroll
    for (int fm = 0; fm < 2; ++fm)
#pragma unroll
        for (int fn = 0; fn < 2; ++fn) {
            const int nn = n0 + wn * 32 + fn * 16 + (lane & 15);
            float* od = O + ((size_t)(nn >> 6) * SEQL) * HD + (nn & 63);
#pragma unroll
            for (int r = 0; r < 4; ++r) {
                const int mm = m0 + wm * 32 + fm * 16 + (lane >> 4) * 4 + r;
                od[(size_t)mm * HD] = acc[fm][fn][r];
            }
        }
}

// One wave per (head, query). Produces rel_bias, attn_weights, attn_output.
__global__ __launch_bounds__(256) void k_attn(
    const float* __restrict__ q, const float* __restrict__ k,
    const float* __restrict__ v, const int* __restrict__ xlen,
    const float* __restrict__ rbw,
    float* __restrict__ relb, float* __restrict__ aw, float* __restrict__ ao) {
    const int hh = blockIdx.x;
    const int q0 = blockIdx.y * 4;
    __shared__ float Ks[SEQL][HD + 4];   // 272B rows: b128 reads are bijective (BW floor)
    __shared__ float ps[4][SEQL];
    const int tid = threadIdx.x;
    const float* __restrict__ kb = k + (size_t)hh * SEQL * HD;
    const float* __restrict__ vb = v + (size_t)hh * SEQL * HD;
    const float4* kb4 = reinterpret_cast<const float4*>(kb);
#pragma unroll
    for (int i = 0; i < 8; ++i) {        // stage K head as float4
        const int e4 = tid + i * 256;    // 2048 float4 slots
        const float4 kv = kb4[e4];
        *reinterpret_cast<float4*>(&Ks[e4 >> 4][(e4 & 15) * 4]) = kv;
    }
    const int w = tid >> 6, lane = tid & 63;
    const int qi = q0 + w;
    const float4* qrow4 = reinterpret_cast<const float4*>(q + (size_t)(hh * SEQL + qi) * HD);
    float4 qr[16];
#pragma unroll
    for (int i = 0; i < 16; ++i) qr[i] = qrow4[i];   // wave-uniform q row in regs
    __syncthreads();
    const int xl = xlen[0];
    float lg[2];
#pragma unroll
    for (int p = 0; p < 2; ++p) {
        const int kk = lane + p * 64;
        float acc = 0.0f;
#pragma unroll
        for (int d4 = 0; d4 < 16; ++d4) {
            const float4 kv = *reinterpret_cast<const float4*>(&Ks[kk][d4 * 4]);
            acc += qr[d4].x * kv.x + qr[d4].y * kv.y + qr[d4].z * kv.z + qr[d4].w * kv.w;
        }
        float bias = rbw[hh * 32 + rel_bucket(kk, qi)];
        if (kk >= xl) bias += -1e9f;
        relb[hh * SEQL * SEQL + kk * SEQL + qi] = bias;   // rel_bias (each elem once)
        acc += bias;
        lg[p] = acc;
        aw[hh * SEQL * SEQL + qi * SEQL + kk] = acc;      // attn_weights
    }
    float mx = fmaxf(lg[0], lg[1]);
#pragma unroll
    for (int o = 32; o > 0; o >>= 1) mx = fmaxf(mx, __shfl_xor(mx, o));
    const float e0 = expf(lg[0] - mx);
    const float e1 = expf(lg[1] - mx);
    float sm = e0 + e1;
#pragma unroll
    for (int o = 32; o > 0; o >>= 1) sm += __shfl_xor(sm, o);
    const float inv = 1.0f / sm;
    ps[w][lane]      = e0 * inv;
    ps[w][lane + 64] = e1 * inv;
    __syncthreads();
    float accv = 0.0f;
#pragma unroll 8
    for (int kk4 = 0; kk4 < 32; ++kk4) {
        const float4 p4 = *reinterpret_cast<const float4*>(&ps[w][kk4 * 4]);
        accv += p4.x * vb[(kk4 * 4 + 0) * HD + lane]
              + p4.y * vb[(kk4 * 4 + 1) * HD + lane]
              + p4.z * vb[(kk4 * 4 + 2) * HD + lane]
              + p4.w * vb[(kk4 * 4 + 3) * HD + lane];
    }
    ao[(size_t)(hh * SEQL + qi) * HD + lane] = accv;
}

extern "C" void kernel_launch(void* const* d_in, const int* in_sizes, int n_in,
                              void* d_out, int out_size, void* d_ws, size_t ws_size,
                              hipStream_t stream) {
    const int*   x     = (const int*)d_in[0];
    const int*   xlen  = (const int*)d_in[1];
    const float* embed = (const float*)d_in[2];
    const float* scale = (const float*)d_in[3];
    const float* rbw   = (const float*)d_in[4];
    const float* qw    = (const float*)d_in[5];
    const float* kw    = (const float*)d_in[6];
    const float* vw    = (const float*)d_in[7];

    float* out  = (float*)d_out;
    float* relb = out;                          // (8,128,128)
    float* aw   = out + NH * SEQL * SEQL;       // (8,128,128)
    float* ao   = out + 2 * NH * SEQL * SEQL;   // (8,128,64)

    char* wsb = (char*)d_ws;
    ushort_t* hbf = (ushort_t*)wsb;                          // 128x512 bf16
    ushort_t* wt  = (ushort_t*)(wsb + 131072);               // 3 x 512x512 bf16 (W^T)
    float* q = (float*)(wsb + 1703936);                      // (8,128,64) f32 head-split
    float* k = q + SEQL * DM;
    float* v = k + SEQL * DM;

    k_prep<<<SEQL + 192, 256, 0, stream>>>(x, xlen, embed, scale, qw, kw, vw, hbf, wt);
    k_qkv<<<dim3(8, 2, 3), 256, 0, stream>>>(hbf, wt, q, k, v);
    k_attn<<<dim3(NH, SEQL / 4), 256, 0, stream>>>(q, k, v, xlen, rbw, relb, aw, ao);
}

// Round 3
// 18.140 us; speedup vs baseline: 2.2111x; 1.3131x over previous
//
#include <hip/hip_runtime.h>

#define SEQL 128
#define DM   512
#define NH   8
#define HD   64

typedef unsigned short ushort_t;
typedef unsigned int   uint_t;
typedef __attribute__((ext_vector_type(8))) __bf16 bf16x8;
typedef __attribute__((ext_vector_type(4))) float  f32x4;

__device__ __forceinline__ ushort_t f2bf(float f) {
    uint_t u = __float_as_uint(f);
    u += 0x7fffu + ((u >> 16) & 1u);       // RNE
    return (ushort_t)(u >> 16);
}

// rp_bucket with rel_pos = i - j  =>  n = -rel_pos = j - i
__device__ __forceinline__ int rel_bucket(int i, int j) {
    int n = j - i;
    int ret = 0;
    if (n < 0) { ret = 16; n = -n; }
    if (n < 8) return ret + n;
    float nf = (float)n;
    int vil = 8 + (int)((logf(nf * 0.125f) / logf(16.0f)) * 8.0f);
    vil = vil < 15 ? vil : 15;
    return ret + vil;
}

// Fused: h-tile (embed+RMS+scale+mask -> bf16, LDS) + C = h @ W via MFMA.
// grid (8 n-tiles, 2 m-tiles, 3 weights), 256 thr = 4 waves (2m x 2n).
// A: full 64x512 bf16 panel in LDS, chunk-XOR swizzle (write once, read 8 iters).
// B: per-iter 64k x 64n tile, column-gather f32 -> bf16, [n][k] XOR-swizzled, dbuf.
__global__ __launch_bounds__(256) void k_qkv_fused(
    const int* __restrict__ x, const int* __restrict__ xlen,
    const float* __restrict__ embed, const float* __restrict__ scale,
    const float* __restrict__ qw, const float* __restrict__ kw,
    const float* __restrict__ vw,
    float* __restrict__ q, float* __restrict__ k, float* __restrict__ v) {
    __shared__ ushort_t Ash[64 * 512];      // 64 KB: row m at m*1024B, chunk c at ((c^(m&7))<<4)
    __shared__ ushort_t Bsh[2][64 * 64];    // 2 x 8 KB: row n at n*128B, chunk c at ((c^(n&7))<<4)
    const int t  = threadIdx.x;
    const int n0 = blockIdx.x * 64;
    const int m0 = blockIdx.y * 64;
    const int wi = blockIdx.z;
    const float* __restrict__ W = (wi == 0) ? qw : (wi == 1) ? kw : vw;
    float* __restrict__ O       = (wi == 0) ? q  : (wi == 1) ? k  : v;
    const int xl = xlen[0];

    // ---- issue B tile 0 loads (column-gather: lane n, 16 k's) ----
    const int nloc = t & 63, khq = t >> 6;       // khq: which 16-k quarter
    const float* __restrict__ wcol = W + n0 + nloc;
    float rc[16];
#pragma unroll
    for (int i = 0; i < 16; ++i) rc[i] = wcol[(size_t)(khq * 16 + i) * DM];

    // ---- h phase: 2 passes x 32 rows, 8 threads per row ----
    const int lane7 = t & 7;
#pragma unroll
    for (int p = 0; p < 2; ++p) {
        const int mloc = p * 32 + (t >> 3);
        const int m    = m0 + mloc;
        const int tok  = x[m];
        const float4* er4 = reinterpret_cast<const float4*>(embed + (size_t)tok * DM);
        float4 va[8], vb[8];
#pragma unroll
        for (int j = 0; j < 8; ++j) {
            va[j] = er4[lane7 * 2 + j * 16];
            vb[j] = er4[lane7 * 2 + j * 16 + 1];
        }
        float ss = 0.0f;
#pragma unroll
        for (int j = 0; j < 8; ++j) {
            ss += va[j].x * va[j].x + va[j].y * va[j].y + va[j].z * va[j].z + va[j].w * va[j].w;
            ss += vb[j].x * vb[j].x + vb[j].y * vb[j].y + vb[j].z * vb[j].z + vb[j].w * vb[j].w;
        }
        ss += __shfl_xor(ss, 1);
        ss += __shfl_xor(ss, 2);
        ss += __shfl_xor(ss, 4);
        float inv = rsqrtf(ss * (1.0f / DM) + 1e-6f);
        if (m >= xl) inv = 0.0f;                 // length mask (exact zero)
        const float4* sc4 = reinterpret_cast<const float4*>(scale);
#pragma unroll
        for (int j = 0; j < 8; ++j) {
            const int c = lane7 + 8 * j;         // bf16 16B-chunk index (0..63)
            const float4 s0 = sc4[c * 2];
            const float4 s1 = sc4[c * 2 + 1];
            ushort_t u[8];
            u[0] = f2bf(va[j].x * inv * s0.x);  u[1] = f2bf(va[j].y * inv * s0.y);
            u[2] = f2bf(va[j].z * inv * s0.z);  u[3] = f2bf(va[j].w * inv * s0.w);
            u[4] = f2bf(vb[j].x * inv * s1.x);  u[5] = f2bf(vb[j].y * inv * s1.y);
            u[6] = f2bf(vb[j].z * inv * s1.z);  u[7] = f2bf(vb[j].w * inv * s1.w);
            *reinterpret_cast<uint4*>((char*)Ash + mloc * 1024 + ((c ^ (mloc & 7)) << 4)) =
                *reinterpret_cast<const uint4*>(u);
        }
    }

    // ---- write B0, prefetch B1 ----
    {
        ushort_t u[16];
#pragma unroll
        for (int i = 0; i < 16; ++i) u[i] = f2bf(rc[i]);
        char* base = (char*)Bsh + nloc * 128;
        *reinterpret_cast<uint4*>(base + (((khq * 2 + 0) ^ (nloc & 7)) << 4)) =
            *reinterpret_cast<const uint4*>(&u[0]);
        *reinterpret_cast<uint4*>(base + (((khq * 2 + 1) ^ (nloc & 7)) << 4)) =
            *reinterpret_cast<const uint4*>(&u[8]);
    }
#pragma unroll
    for (int i = 0; i < 16; ++i) rc[i] = wcol[(size_t)(64 + khq * 16 + i) * DM];
    __syncthreads();

    const int wid = t >> 6, lane = t & 63;
    const int wm = wid >> 1, wn = wid & 1;
    const int g = lane >> 4, l15 = lane & 15;
    f32x4 acc[2][2] = {};

#pragma unroll
    for (int it = 0; it < 8; ++it) {
        // fragment reads (A from static panel, B from dbuf) + 8 MFMA
        bf16x8 af[2][2], bfr[2][2];
#pragma unroll
        for (int fm = 0; fm < 2; ++fm) {
            const int ml = wm * 32 + fm * 16 + l15;
#pragma unroll
            for (int kh = 0; kh < 2; ++kh) {
                const int c = it * 8 + kh * 4 + g;
                af[fm][kh] = *reinterpret_cast<const bf16x8*>(
                    (const char*)Ash + ml * 1024 + ((c ^ (ml & 7)) << 4));
            }
        }
#pragma unroll
        for (int fn = 0; fn < 2; ++fn) {
            const int nl = wn * 32 + fn * 16 + l15;
#pragma unroll
            for (int kh = 0; kh < 2; ++kh) {
                const int c = kh * 4 + g;
                bfr[fn][kh] = *reinterpret_cast<const bf16x8*>(
                    (const char*)Bsh + (it & 1) * 8192 + nl * 128 + ((c ^ (nl & 7)) << 4));
            }
        }
#pragma unroll
        for (int kh = 0; kh < 2; ++kh)
#pragma unroll
            for (int fm = 0; fm < 2; ++fm)
#pragma unroll
                for (int fn = 0; fn < 2; ++fn)
                    acc[fm][fn] = __builtin_amdgcn_mfma_f32_16x16x32_bf16(
                        af[fm][kh], bfr[fn][kh], acc[fm][fn], 0, 0, 0);

        if (it < 7) {
            // write tile it+1 (regs -> LDS), then prefetch tile it+2
            ushort_t u[16];
#pragma unroll
            for (int i = 0; i < 16; ++i) u[i] = f2bf(rc[i]);
            char* base = (char*)Bsh + ((it + 1) & 1) * 8192 + nloc * 128;
            *reinterpret_cast<uint4*>(base + (((khq * 2 + 0) ^ (nloc & 7)) << 4)) =
                *reinterpret_cast<const uint4*>(&u[0]);
            *reinterpret_cast<uint4*>(base + (((khq * 2 + 1) ^ (nloc & 7)) << 4)) =
                *reinterpret_cast<const uint4*>(&u[8]);
            if (it < 6) {
#pragma unroll
                for (int i = 0; i < 16; ++i)
                    rc[i] = wcol[(size_t)((it + 2) * 64 + khq * 16 + i) * DM];
            }
        }
        __syncthreads();
    }

    // C/D layout: col = lane&15, row = (lane>>4)*4 + r
#pragma unroll
    for (int fm = 0; fm < 2; ++fm)
#pragma unroll
        for (int fn = 0; fn < 2; ++fn) {
            const int nn = n0 + wn * 32 + fn * 16 + l15;
            float* od = O + ((size_t)(nn >> 6) * SEQL) * HD + (nn & 63);
#pragma unroll
            for (int r = 0; r < 4; ++r) {
                const int mm = m0 + wm * 32 + fm * 16 + g * 4 + r;
                od[(size_t)mm * HD] = acc[fm][fn][r];
            }
        }
}

// One wave per (head, query). Produces rel_bias, attn_weights, attn_output.
__global__ __launch_bounds__(256) void k_attn(
    const float* __restrict__ q, const float* __restrict__ k,
    const float* __restrict__ v, const int* __restrict__ xlen,
    const float* __restrict__ rbw,
    float* __restrict__ relb, float* __restrict__ aw, float* __restrict__ ao) {
    const int hh = blockIdx.x;
    const int q0 = blockIdx.y * 4;
    __shared__ float Ks[SEQL][HD + 4];
    __shared__ float ps[4][SEQL];
    const int tid = threadIdx.x;
    const float* __restrict__ kb = k + (size_t)hh * SEQL * HD;
    const float* __restrict__ vb = v + (size_t)hh * SEQL * HD;
    const float4* kb4 = reinterpret_cast<const float4*>(kb);
#pragma unroll
    for (int i = 0; i < 8; ++i) {
        const int e4 = tid + i * 256;
        const float4 kv = kb4[e4];
        *reinterpret_cast<float4*>(&Ks[e4 >> 4][(e4 & 15) * 4]) = kv;
    }
    const int w = tid >> 6, lane = tid & 63;
    const int qi = q0 + w;
    const float4* qrow4 = reinterpret_cast<const float4*>(q + (size_t)(hh * SEQL + qi) * HD);
    float4 qr[16];
#pragma unroll
    for (int i = 0; i < 16; ++i) qr[i] = qrow4[i];
    __syncthreads();
    const int xl = xlen[0];
    float lg[2];
#pragma unroll
    for (int p = 0; p < 2; ++p) {
        const int kk = lane + p * 64;
        float acc = 0.0f;
#pragma unroll
        for (int d4 = 0; d4 < 16; ++d4) {
            const float4 kv = *reinterpret_cast<const float4*>(&Ks[kk][d4 * 4]);
            acc += qr[d4].x * kv.x + qr[d4].y * kv.y + qr[d4].z * kv.z + qr[d4].w * kv.w;
        }
        float bias = rbw[hh * 32 + rel_bucket(kk, qi)];
        if (kk >= xl) bias += -1e9f;
        relb[hh * SEQL * SEQL + kk * SEQL + qi] = bias;
        acc += bias;
        lg[p] = acc;
        aw[hh * SEQL * SEQL + qi * SEQL + kk] = acc;
    }
    float mx = fmaxf(lg[0], lg[1]);
#pragma unroll
    for (int o = 32; o > 0; o >>= 1) mx = fmaxf(mx, __shfl_xor(mx, o));
    const float e0 = expf(lg[0] - mx);
    const float e1 = expf(lg[1] - mx);
    float sm = e0 + e1;
#pragma unroll
    for (int o = 32; o > 0; o >>= 1) sm += __shfl_xor(sm, o);
    const float inv = 1.0f / sm;
    ps[w][lane]      = e0 * inv;
    ps[w][lane + 64] = e1 * inv;
    __syncthreads();
    float accv = 0.0f;
#pragma unroll 8
    for (int kk4 = 0; kk4 < 32; ++kk4) {
        const float4 p4 = *reinterpret_cast<const float4*>(&ps[w][kk4 * 4]);
        accv += p4.x * vb[(kk4 * 4 + 0) * HD + lane]
              + p4.y * vb[(kk4 * 4 + 1) * HD + lane]
              + p4.z * vb[(kk4 * 4 + 2) * HD + lane]
              + p4.w * vb[(kk4 * 4 + 3) * HD + lane];
    }
    ao[(size_t)(hh * SEQL + qi) * HD + lane] = accv;
}

extern "C" void kernel_launch(void* const* d_in, const int* in_sizes, int n_in,
                              void* d_out, int out_size, void* d_ws, size_t ws_size,
                              hipStream_t stream) {
    const int*   x     = (const int*)d_in[0];
    const int*   xlen  = (const int*)d_in[1];
    const float* embed = (const float*)d_in[2];
    const float* scale = (const float*)d_in[3];
    const float* rbw   = (const float*)d_in[4];
    const float* qw    = (const float*)d_in[5];
    const float* kw    = (const float*)d_in[6];
    const float* vw    = (const float*)d_in[7];

    float* out  = (float*)d_out;
    float* relb = out;                          // (8,128,128)
    float* aw   = out + NH * SEQL * SEQL;       // (8,128,128)
    float* ao   = out + 2 * NH * SEQL * SEQL;   // (8,128,64)

    float* ws = (float*)d_ws;
    float* q  = ws;                    // (8,128,64) f32 head-split
    float* k  = q + SEQL * DM;
    float* v  = k + SEQL * DM;

    k_qkv_fused<<<dim3(8, 2, 3), 256, 0, stream>>>(x, xlen, embed, scale, qw, kw, vw, q, k, v);
    k_attn<<<dim3(NH, SEQL / 4), 256, 0, stream>>>(q, k, v, xlen, rbw, relb, aw, ao);
}